// Round 5
// baseline (320.722 us; speedup 1.0000x reference)
//
#include <hip/hip_runtime.h>

#define PTS    4096
#define TPB    256
#define PPB    64      // points per block (one per lane of the merge wave)
#define QTR    1024    // candidates scanned per thread (4-way split)
#define NSUB   32      // substream minima per thread -- fits in VGPRs (no spill)
#define CAP    36      // collect slots per thread
#define NCLOUD 16
#define UMAX   0xFFFFFFFFu

// insert key into unsorted top-N (s holds the N smallest seen, cmax = max of s)
template<int N>
__device__ __forceinline__ void insN(unsigned key, unsigned (&s)[N], unsigned &cmax) {
  if (key < cmax) {
    bool done = false;
#pragma unroll
    for (int i = 0; i < N; ++i) {
      bool c = (!done) && (s[i] == cmax);
      s[i] = c ? key : s[i];
      done = done || c;
    }
    cmax = s[0];
#pragma unroll
    for (int i = 1; i < N; ++i) cmax = (s[i] > cmax) ? s[i] : cmax;
  }
}

__global__ __launch_bounds__(TPB, 4) void knn_cov(const float* __restrict__ x,
                                                  float* __restrict__ out) {
  __shared__ unsigned scol[CAP * TPB];  // 36 KB: per-thread collect columns
  __shared__ unsigned scnt[TPB];        // 1 KB  (total ~37 KB -> 4 blocks/CU)

  const int tid  = threadIdx.x;
  const int lane = tid & 63;
  const int h     = __builtin_amdgcn_readfirstlane(tid >> 6);  // wave = quarter
  const int cloud = blockIdx.x >> 6;          // 64 chunks per cloud
  const int chunk = blockIdx.x & 63;
  const int p     = chunk * PPB + lane;       // in-cloud point for this lane

  const float* __restrict__ xc = x + (size_t)cloud * PTS * 3;

  const float px = xc[p * 3 + 0];
  const float py = xc[p * 3 + 1];
  const float pz = xc[p * 3 + 2];

  const int c0 = h * QTR;                     // this wave's candidate quarter
  const float* __restrict__ cc = xc + (size_t)c0 * 3;

  // ---- pass 1: 32 substream minima in registers (7 VALU/cand, no DS, no spill)
  float m[NSUB];
#pragma unroll
  for (int j = 0; j < NSUB; ++j) m[j] = 3.4e38f;
  for (int t0 = 0; t0 < QTR; t0 += NSUB) {
#pragma unroll
    for (int j = 0; j < NSUB; ++j) {
      const int ci = t0 + j;
      const float qx = cc[ci * 3 + 0];
      const float qy = cc[ci * 3 + 1];
      const float qz = cc[ci * 3 + 2];
      const float dx = qx - px, dy = qy - py, dz = qz - pz;
      const float d  = fmaf(dz, dz, fmaf(dy, dy, dx * dx));
      m[j] = fminf(m[j], d);                  // static index -> stays in VGPR
    }
  }

  // ---- threshold = 17th smallest of 32 minima (rank 17 absorbs self d=0;
  //      top-16 occupy <=16 substreams => T >= true 16th-neighbor distance)
  unsigned s17[17], cm;
#pragma unroll
  for (int j = 0; j < 17; ++j) s17[j] = __float_as_uint(m[j]);
  cm = s17[0];
#pragma unroll
  for (int j = 1; j < 17; ++j) cm = (s17[j] > cm) ? s17[j] : cm;
#pragma unroll
  for (int j = 17; j < NSUB; ++j) insN<17>(__float_as_uint(m[j]), s17, cm);
  const float Tval = __uint_as_float(cm);

  // ---- pass 2: collect all d <= T into LDS columns (clamped slot)
  unsigned cnt = 0;
  for (int t0 = 0; t0 < QTR; t0 += 8) {
#pragma unroll
    for (int j = 0; j < 8; ++j) {
      const int ci = t0 + j;
      const float qx = cc[ci * 3 + 0];
      const float qy = cc[ci * 3 + 1];
      const float qz = cc[ci * 3 + 2];
      const float dx = qx - px, dy = qy - py, dz = qz - pz;
      const float d  = fmaf(dz, dz, fmaf(dy, dy, dx * dx));
      if (d <= Tval) {
        const unsigned slot = (cnt < (unsigned)CAP) ? cnt : (unsigned)(CAP - 1);
        scol[slot * TPB + tid] =
            (__float_as_uint(d) & 0xFFFFF000u) | (unsigned)(c0 + ci);
        cnt++;
      }
    }
  }

  // ---- overflow fallback (rare, ~4 sigma): exact top-17 rescan of this quarter
  if (cnt > (unsigned)CAP) {
    unsigned sf[17], cmf = UMAX;
#pragma unroll
    for (int j = 0; j < 17; ++j) sf[j] = UMAX;
#pragma unroll 4
    for (int ci = 0; ci < QTR; ++ci) {
      const float qx = cc[ci * 3 + 0];
      const float qy = cc[ci * 3 + 1];
      const float qz = cc[ci * 3 + 2];
      const float dx = qx - px, dy = qy - py, dz = qz - pz;
      const float d  = fmaf(dz, dz, fmaf(dy, dy, dx * dx));
      const unsigned kb = (__float_as_uint(d) & 0xFFFFF000u) | (unsigned)(c0 + ci);
      insN<17>(kb, sf, cmf);
    }
#pragma unroll
    for (int j = 0; j < 17; ++j) scol[j * TPB + tid] = sf[j];
    cnt = 17;
  }
  scnt[tid] = cnt;
  __syncthreads();

  // ---- merge the 4 quarters' candidate sets (wave 0), cov, store
  if (tid < PPB) {
    unsigned s16[16], cm16 = UMAX;
#pragma unroll
    for (int j = 0; j < 16; ++j) s16[j] = UMAX;
    const unsigned selfk = (unsigned)p;  // self: d==+0 exactly -> key = index
#pragma unroll
    for (int k = 0; k < 4; ++k) {
      const int col = k * PPB + tid;
      const unsigned n = scnt[col];
      unsigned w = n;
#pragma unroll
      for (int off = 32; off >= 1; off >>= 1) {
        unsigned o = (unsigned)__shfl_xor((int)w, off, 64);
        w = (o > w) ? o : w;
      }
      for (unsigned j = 0; j < w; ++j) {
        unsigned kb = (j < n) ? scol[j * TPB + col] : UMAX;
        kb = (kb == selfk) ? UMAX : kb;
        insN<16>(kb, s16, cm16);
      }
    }

    // gather neighbor coords (L1/L2-resident), raw moments -> covariance
    float Sx = 0, Sy = 0, Sz = 0;
    float Sxx = 0, Sxy = 0, Sxz = 0, Syy = 0, Syz = 0, Szz = 0;
#pragma unroll
    for (int j = 0; j < 16; ++j) {
      const int idx = (int)(s16[j] & 0xFFFu);
      const float nx = xc[idx * 3 + 0];
      const float ny = xc[idx * 3 + 1];
      const float nz = xc[idx * 3 + 2];
      Sx += nx; Sy += ny; Sz += nz;
      Sxx = fmaf(nx, nx, Sxx); Sxy = fmaf(nx, ny, Sxy); Sxz = fmaf(nx, nz, Sxz);
      Syy = fmaf(ny, ny, Syy); Syz = fmaf(ny, nz, Syz); Szz = fmaf(nz, nz, Szz);
    }
    const float sc = 0.0625f;
    const float mx = Sx * sc, my = Sy * sc, mz = Sz * sc;
    const float cxx = fmaf(-mx, mx, Sxx * sc);
    const float cxy = fmaf(-mx, my, Sxy * sc);
    const float cxz = fmaf(-mx, mz, Sxz * sc);
    const float cyy = fmaf(-my, my, Syy * sc);
    const float cyz = fmaf(-my, mz, Syz * sc);
    const float czz = fmaf(-mz, mz, Szz * sc);

    const int gid = cloud * PTS + p;
    float4* o4 = (float4*)(out + (size_t)gid * 12);
    o4[0] = make_float4(px, py, pz, cxx);
    o4[1] = make_float4(cxy, cxz, cxy, cyy);
    o4[2] = make_float4(cyz, cxz, cyz, czz);
  }
}

extern "C" void kernel_launch(void* const* d_in, const int* in_sizes, int n_in,
                              void* d_out, int out_size, void* d_ws, size_t ws_size,
                              hipStream_t stream) {
  const float* x = (const float*)d_in[0];
  float* out = (float*)d_out;
  dim3 grid(NCLOUD * (PTS / PPB));  // 16 clouds x 64 chunks = 1024 blocks = 4/CU
  knn_cov<<<grid, TPB, 0, stream>>>(x, out);
}

// Round 6
// 319.135 us; speedup vs baseline: 1.0050x; 1.0050x over previous
//
#include <hip/hip_runtime.h>

#define PTS    4096
#define TPB    256
#define PPB    64      // points per block (one per lane of the merge wave)
#define QTR    1024    // candidates scanned per thread (4-way split)
#define NSUB   32      // substream minima (register-resident target)
#define CAP    36      // collect slots per thread
#define NCLOUD 16
#define UMAX   0xFFFFFFFFu

// insert key into unsorted top-N (s holds the N smallest seen, cmax = max of s)
template<int N>
__device__ __forceinline__ void insN(unsigned key, unsigned (&s)[N], unsigned &cmax) {
  if (key < cmax) {
    bool done = false;
#pragma unroll
    for (int i = 0; i < N; ++i) {
      bool c = (!done) && (s[i] == cmax);
      s[i] = c ? key : s[i];
      done = done || c;
    }
    cmax = s[0];
#pragma unroll
    for (int i = 1; i < N; ++i) cmax = (s[i] > cmax) ? s[i] : cmax;
  }
}

__global__ __launch_bounds__(TPB, 4) void knn_cov(const float* __restrict__ x,
                                                  float* __restrict__ out) {
  __shared__ unsigned scol[CAP * TPB];  // 36 KB: per-thread collect columns
  __shared__ unsigned scnt[TPB];        // 1 KB  (total ~37 KB -> 4 blocks/CU)

  const int tid  = threadIdx.x;
  const int lane = tid & 63;
  const int h     = __builtin_amdgcn_readfirstlane(tid >> 6);  // wave = quarter
  const int cloud = blockIdx.x >> 6;          // 64 chunks per cloud
  const int chunk = blockIdx.x & 63;
  const int p     = chunk * PPB + lane;       // in-cloud point for this lane

  const float* __restrict__ xc = x + (size_t)cloud * PTS * 3;

  const float px = xc[p * 3 + 0];
  const float py = xc[p * 3 + 1];
  const float pz = xc[p * 3 + 2];

  const int c0 = h * QTR;                     // this wave's candidate quarter
  const float* __restrict__ cc = xc + (size_t)c0 * 3;

  // ---- pass 1: 32 substream minima; candidates consumed in groups of 8 so
  //      load batches stay small enough to software-pipeline (r3 structure).
  float m[NSUB];
#pragma unroll
  for (int j = 0; j < NSUB; ++j) m[j] = 3.4e38f;
#pragma unroll 1
  for (int t0 = 0; t0 < QTR; t0 += NSUB) {
#pragma unroll
    for (int g = 0; g < NSUB / 8; ++g) {
#pragma unroll
      for (int j = 0; j < 8; ++j) {
        const int ci = t0 + g * 8 + j;
        const float qx = cc[ci * 3 + 0];
        const float qy = cc[ci * 3 + 1];
        const float qz = cc[ci * 3 + 2];
        const float dx = qx - px, dy = qy - py, dz = qz - pz;
        const float d  = fmaf(dz, dz, fmaf(dy, dy, dx * dx));
        const int mi   = g * 8 + j;           // static index 0..31
        m[mi] = fminf(m[mi], d);
      }
    }
  }

  // ---- threshold = 17th smallest of 32 minima (rank 17 absorbs self d=0;
  //      top-16 occupy <=16 substreams => T >= true 16th-neighbor distance)
  unsigned s17[17], cm;
#pragma unroll
  for (int j = 0; j < 17; ++j) s17[j] = __float_as_uint(m[j]);
  cm = s17[0];
#pragma unroll
  for (int j = 1; j < 17; ++j) cm = (s17[j] > cm) ? s17[j] : cm;
#pragma unroll
  for (int j = 17; j < NSUB; ++j) insN<17>(__float_as_uint(m[j]), s17, cm);
  const float Tval = __uint_as_float(cm);

  // ---- pass 2: collect all d <= T into LDS columns (groups of 8, unroll 1)
  unsigned cnt = 0;
#pragma unroll 1
  for (int t0 = 0; t0 < QTR; t0 += 8) {
#pragma unroll
    for (int j = 0; j < 8; ++j) {
      const int ci = t0 + j;
      const float qx = cc[ci * 3 + 0];
      const float qy = cc[ci * 3 + 1];
      const float qz = cc[ci * 3 + 2];
      const float dx = qx - px, dy = qy - py, dz = qz - pz;
      const float d  = fmaf(dz, dz, fmaf(dy, dy, dx * dx));
      if (d <= Tval) {
        const unsigned slot = (cnt < (unsigned)CAP) ? cnt : (unsigned)(CAP - 1);
        scol[slot * TPB + tid] =
            (__float_as_uint(d) & 0xFFFFF000u) | (unsigned)(c0 + ci);
        cnt++;
      }
    }
  }

  // ---- overflow fallback (rare): exact top-17 rescan of this quarter
  if (cnt > (unsigned)CAP) {
    unsigned sf[17], cmf = UMAX;
#pragma unroll
    for (int j = 0; j < 17; ++j) sf[j] = UMAX;
#pragma unroll 1
    for (int ci = 0; ci < QTR; ++ci) {
      const float qx = cc[ci * 3 + 0];
      const float qy = cc[ci * 3 + 1];
      const float qz = cc[ci * 3 + 2];
      const float dx = qx - px, dy = qy - py, dz = qz - pz;
      const float d  = fmaf(dz, dz, fmaf(dy, dy, dx * dx));
      const unsigned kb = (__float_as_uint(d) & 0xFFFFF000u) | (unsigned)(c0 + ci);
      insN<17>(kb, sf, cmf);
    }
#pragma unroll
    for (int j = 0; j < 17; ++j) scol[j * TPB + tid] = sf[j];
    cnt = 17;
  }
  scnt[tid] = cnt;
  __syncthreads();

  // ---- merge the 4 quarters' candidate sets (wave 0), cov, store
  if (tid < PPB) {
    unsigned s16[16], cm16 = UMAX;
#pragma unroll
    for (int j = 0; j < 16; ++j) s16[j] = UMAX;
    const unsigned selfk = (unsigned)p;  // self: d==+0 exactly -> key = index
#pragma unroll
    for (int k = 0; k < 4; ++k) {
      const int col = k * PPB + tid;
      const unsigned n = scnt[col];
      unsigned w = n;
#pragma unroll
      for (int off = 32; off >= 1; off >>= 1) {
        unsigned o = (unsigned)__shfl_xor((int)w, off, 64);
        w = (o > w) ? o : w;
      }
      for (unsigned j = 0; j < w; ++j) {
        unsigned kb = (j < n) ? scol[j * TPB + col] : UMAX;
        kb = (kb == selfk) ? UMAX : kb;
        insN<16>(kb, s16, cm16);
      }
    }

    // gather neighbor coords (L1/L2-resident), raw moments -> covariance
    float Sx = 0, Sy = 0, Sz = 0;
    float Sxx = 0, Sxy = 0, Sxz = 0, Syy = 0, Syz = 0, Szz = 0;
#pragma unroll
    for (int j = 0; j < 16; ++j) {
      const int idx = (int)(s16[j] & 0xFFFu);
      const float nx = xc[idx * 3 + 0];
      const float ny = xc[idx * 3 + 1];
      const float nz = xc[idx * 3 + 2];
      Sx += nx; Sy += ny; Sz += nz;
      Sxx = fmaf(nx, nx, Sxx); Sxy = fmaf(nx, ny, Sxy); Sxz = fmaf(nx, nz, Sxz);
      Syy = fmaf(ny, ny, Syy); Syz = fmaf(ny, nz, Syz); Szz = fmaf(nz, nz, Szz);
    }
    const float sc = 0.0625f;
    const float mx = Sx * sc, my = Sy * sc, mz = Sz * sc;
    const float cxx = fmaf(-mx, mx, Sxx * sc);
    const float cxy = fmaf(-mx, my, Sxy * sc);
    const float cxz = fmaf(-mx, mz, Sxz * sc);
    const float cyy = fmaf(-my, my, Syy * sc);
    const float cyz = fmaf(-my, mz, Syz * sc);
    const float czz = fmaf(-mz, mz, Szz * sc);

    const int gid = cloud * PTS + p;
    float4* o4 = (float4*)(out + (size_t)gid * 12);
    o4[0] = make_float4(px, py, pz, cxx);
    o4[1] = make_float4(cxy, cxz, cxy, cyy);
    o4[2] = make_float4(cyz, cxz, cyz, czz);
  }
}

extern "C" void kernel_launch(void* const* d_in, const int* in_sizes, int n_in,
                              void* d_out, int out_size, void* d_ws, size_t ws_size,
                              hipStream_t stream) {
  const float* x = (const float*)d_in[0];
  float* out = (float*)d_out;
  dim3 grid(NCLOUD * (PTS / PPB));  // 16 clouds x 64 chunks = 1024 blocks = 4/CU
  knn_cov<<<grid, TPB, 0, stream>>>(x, out);
}

// Round 7
// 215.517 us; speedup vs baseline: 1.4882x; 1.4808x over previous
//
#include <hip/hip_runtime.h>

#define PTS    4096
#define TPB    256
#define PPB    64      // points per block (one per lane of the merge wave)
#define QTR    1024    // candidates scanned per thread (4-way split)
#define QPR    512     // pairs per quarter
#define CAP    36      // collect slots per thread
#define NCLOUD 16
#define NPAIRS (NCLOUD * PTS / 2)
#define UMAX   0xFFFFFFFFu

typedef __attribute__((ext_vector_type(2))) float f32x2;

// insert key into unsorted top-N (s holds the N smallest seen, cmax = max of s)
template<int N>
__device__ __forceinline__ void insN(unsigned key, unsigned (&s)[N], unsigned &cmax) {
  if (key < cmax) {
    bool done = false;
#pragma unroll
    for (int i = 0; i < N; ++i) {
      bool c = (!done) && (s[i] == cmax);
      s[i] = c ? key : s[i];
      done = done || c;
    }
    cmax = s[0];
#pragma unroll
    for (int i = 1; i < N; ++i) cmax = (s[i] > cmax) ? s[i] : cmax;
  }
}

// AoS xyz pairs -> pair-interleaved {x0,x1,y0,y1,z0,z1,_,_} (32 B/pair)
__global__ void pair_pack(const float* __restrict__ x, float* __restrict__ ws) {
  const int g = blockIdx.x * TPB + threadIdx.x;  // pair id
  const float* s = x + (size_t)g * 6;
  const float2 f01 = *(const float2*)(s + 0);    // x0 y0
  const float2 f23 = *(const float2*)(s + 2);    // z0 x1
  const float2 f45 = *(const float2*)(s + 4);    // y1 z1
  float* d = ws + (size_t)g * 8;
  *(float4*)(d)     = make_float4(f01.x, f23.y, f01.y, f45.x);  // x0 x1 y0 y1
  *(float2*)(d + 4) = make_float2(f23.x, f45.y);                // z0 z1
}

__global__ __launch_bounds__(TPB, 4) void knn_cov_pk(const float* __restrict__ ws,
                                                     float* __restrict__ out) {
  __shared__ unsigned scol[CAP * TPB];  // 36 KB
  __shared__ unsigned scnt[TPB];        // 1 KB -> 4 blocks/CU

  const int tid  = threadIdx.x;
  const int lane = tid & 63;
  const int h     = __builtin_amdgcn_readfirstlane(tid >> 6);
  const int cloud = blockIdx.x >> 6;
  const int chunk = blockIdx.x & 63;
  const int p     = chunk * PPB + lane;

  const float* __restrict__ wc = ws + (size_t)cloud * (PTS / 2) * 8;

  const float* mp = wc + (size_t)(p >> 1) * 8;
  const int pe = p & 1;
  const float px = mp[0 + pe], py = mp[2 + pe], pz = mp[4 + pe];
  f32x2 vx; vx.x = px; vx.y = px;
  f32x2 vy; vy.x = py; vy.y = py;
  f32x2 vz; vz.x = pz; vz.y = pz;

  const int c0 = h * QTR;
  const float* __restrict__ cp = wc + (size_t)(c0 >> 1) * 8;

  // ---- pass 1: 64 substream minima as 32 packed pairs (r3's m[64] footprint,
  //      half the min/sub/fma instruction count via v_pk_* f32 ops)
  f32x2 m2[32];
#pragma unroll
  for (int j = 0; j < 32; ++j) { m2[j].x = 3.4e38f; m2[j].y = 3.4e38f; }
  for (int t0 = 0; t0 < QPR; t0 += 32) {
#pragma unroll
    for (int g = 0; g < 8; ++g) {
#pragma unroll
      for (int j = 0; j < 4; ++j) {
        const int pi = t0 + g * 4 + j;
        const float4 a  = *(const float4*)(cp + (size_t)pi * 8);
        const f32x2  zz = *(const f32x2*)(cp + (size_t)pi * 8 + 4);
        f32x2 xs; xs.x = a.x; xs.y = a.y;
        f32x2 ys; ys.x = a.z; ys.y = a.w;
        const f32x2 dx = xs - vx, dy = ys - vy, dz = zz - vz;
        const f32x2 d  = dx * dx + dy * dy + dz * dz;
        const int mi   = g * 4 + j;           // static index
        m2[mi] = __builtin_elementwise_min(m2[mi], d);
      }
    }
  }

  // ---- threshold = 17th smallest of 64 minima (rank 17 absorbs self d=0)
  float mm[64];
#pragma unroll
  for (int j = 0; j < 32; ++j) { mm[2 * j] = m2[j].x; mm[2 * j + 1] = m2[j].y; }
  unsigned s17[17], cm;
#pragma unroll
  for (int j = 0; j < 17; ++j) s17[j] = __float_as_uint(mm[j]);
  cm = s17[0];
#pragma unroll
  for (int j = 1; j < 17; ++j) cm = (s17[j] > cm) ? s17[j] : cm;
#pragma unroll
  for (int j = 17; j < 64; ++j) insN<17>(__float_as_uint(mm[j]), s17, cm);
  const float Tval = __uint_as_float(cm);

  // ---- pass 2: collect all d <= T into LDS columns (packed math)
  unsigned cnt = 0;
  for (int t0 = 0; t0 < QPR; t0 += 8) {
#pragma unroll
    for (int j = 0; j < 8; ++j) {
      const int pi = t0 + j;
      const float4 a  = *(const float4*)(cp + (size_t)pi * 8);
      const f32x2  zz = *(const f32x2*)(cp + (size_t)pi * 8 + 4);
      f32x2 xs; xs.x = a.x; xs.y = a.y;
      f32x2 ys; ys.x = a.z; ys.y = a.w;
      const f32x2 dx = xs - vx, dy = ys - vy, dz = zz - vz;
      const f32x2 d  = dx * dx + dy * dy + dz * dz;
      if (d.x <= Tval) {
        const unsigned slot = (cnt < (unsigned)CAP) ? cnt : (unsigned)(CAP - 1);
        scol[slot * TPB + tid] =
            (__float_as_uint(d.x) & 0xFFFFF000u) | (unsigned)(c0 + 2 * pi);
        cnt++;
      }
      if (d.y <= Tval) {
        const unsigned slot = (cnt < (unsigned)CAP) ? cnt : (unsigned)(CAP - 1);
        scol[slot * TPB + tid] =
            (__float_as_uint(d.y) & 0xFFFFF000u) | (unsigned)(c0 + 2 * pi + 1);
        cnt++;
      }
    }
  }

  // ---- overflow fallback (rare): exact top-17 rescan of this quarter
  if (cnt > (unsigned)CAP) {
    unsigned sf[17], cmf = UMAX;
#pragma unroll
    for (int j = 0; j < 17; ++j) sf[j] = UMAX;
    for (int ci = 0; ci < QTR; ++ci) {
      const float* q = cp + (size_t)(ci >> 1) * 8;
      const int e = ci & 1;
      const float dx = q[0 + e] - px, dy = q[2 + e] - py, dz = q[4 + e] - pz;
      const float d  = fmaf(dz, dz, fmaf(dy, dy, dx * dx));
      insN<17>((__float_as_uint(d) & 0xFFFFF000u) | (unsigned)(c0 + ci), sf, cmf);
    }
#pragma unroll
    for (int j = 0; j < 17; ++j) scol[j * TPB + tid] = sf[j];
    cnt = 17;
  }
  scnt[tid] = cnt;
  __syncthreads();

  // ---- merge the 4 quarters' candidate sets (wave 0), cov, store
  if (tid < PPB) {
    unsigned s16[16], cm16 = UMAX;
#pragma unroll
    for (int j = 0; j < 16; ++j) s16[j] = UMAX;
    const unsigned selfk = (unsigned)p;  // self: d==+0 exactly -> key = index
#pragma unroll
    for (int k = 0; k < 4; ++k) {
      const int col = k * PPB + tid;
      const unsigned n = scnt[col];
      unsigned w = n;
#pragma unroll
      for (int off = 32; off >= 1; off >>= 1) {
        unsigned o = (unsigned)__shfl_xor((int)w, off, 64);
        w = (o > w) ? o : w;
      }
      for (unsigned j = 0; j < w; ++j) {
        unsigned kb = (j < n) ? scol[j * TPB + col] : UMAX;
        kb = (kb == selfk) ? UMAX : kb;
        insN<16>(kb, s16, cm16);
      }
    }

    float Sx = 0, Sy = 0, Sz = 0;
    float Sxx = 0, Sxy = 0, Sxz = 0, Syy = 0, Syz = 0, Szz = 0;
#pragma unroll
    for (int j = 0; j < 16; ++j) {
      const int idx = (int)(s16[j] & 0xFFFu);
      const float* q = wc + (size_t)(idx >> 1) * 8;
      const int e = idx & 1;
      const float nx = q[0 + e], ny = q[2 + e], nz = q[4 + e];
      Sx += nx; Sy += ny; Sz += nz;
      Sxx = fmaf(nx, nx, Sxx); Sxy = fmaf(nx, ny, Sxy); Sxz = fmaf(nx, nz, Sxz);
      Syy = fmaf(ny, ny, Syy); Syz = fmaf(ny, nz, Syz); Szz = fmaf(nz, nz, Szz);
    }
    const float sc = 0.0625f;
    const float mx = Sx * sc, my = Sy * sc, mz = Sz * sc;
    const float cxx = fmaf(-mx, mx, Sxx * sc);
    const float cxy = fmaf(-mx, my, Sxy * sc);
    const float cxz = fmaf(-mx, mz, Sxz * sc);
    const float cyy = fmaf(-my, my, Syy * sc);
    const float cyz = fmaf(-my, mz, Syz * sc);
    const float czz = fmaf(-mz, mz, Szz * sc);

    const int gid = cloud * PTS + p;
    float4* o4 = (float4*)(out + (size_t)gid * 12);
    o4[0] = make_float4(px, py, pz, cxx);
    o4[1] = make_float4(cxy, cxz, cxy, cyy);
    o4[2] = make_float4(cyz, cxz, cyz, czz);
  }
}

// ---- r3-exact AoS fallback (used only if ws too small) ----
__global__ __launch_bounds__(TPB, 4) void knn_cov_aos(const float* __restrict__ x,
                                                      float* __restrict__ out) {
  __shared__ unsigned scol[CAP * TPB];
  __shared__ unsigned scnt[TPB];

  const int tid  = threadIdx.x;
  const int lane = tid & 63;
  const int h     = __builtin_amdgcn_readfirstlane(tid >> 6);
  const int cloud = blockIdx.x >> 6;
  const int chunk = blockIdx.x & 63;
  const int p     = chunk * PPB + lane;

  const float* __restrict__ xc = x + (size_t)cloud * PTS * 3;
  const float px = xc[p * 3 + 0], py = xc[p * 3 + 1], pz = xc[p * 3 + 2];
  const int c0 = h * QTR;
  const float* __restrict__ cc = xc + (size_t)c0 * 3;

  float m[64];
#pragma unroll
  for (int j = 0; j < 64; ++j) m[j] = 3.4e38f;
  for (int t0 = 0; t0 < QTR; t0 += 64) {
#pragma unroll
    for (int g = 0; g < 8; ++g) {
#pragma unroll
      for (int j = 0; j < 8; ++j) {
        const int ci = t0 + g * 8 + j;
        const float dx = cc[ci * 3 + 0] - px, dy = cc[ci * 3 + 1] - py,
                    dz = cc[ci * 3 + 2] - pz;
        const float d = fmaf(dz, dz, fmaf(dy, dy, dx * dx));
        const int mi = g * 8 + j;
        m[mi] = fminf(m[mi], d);
      }
    }
  }
  unsigned s17[17], cm;
#pragma unroll
  for (int j = 0; j < 17; ++j) s17[j] = __float_as_uint(m[j]);
  cm = s17[0];
#pragma unroll
  for (int j = 1; j < 17; ++j) cm = (s17[j] > cm) ? s17[j] : cm;
#pragma unroll
  for (int j = 17; j < 64; ++j) insN<17>(__float_as_uint(m[j]), s17, cm);
  const float Tval = __uint_as_float(cm);

  unsigned cnt = 0;
  for (int t0 = 0; t0 < QTR; t0 += 8) {
#pragma unroll
    for (int j = 0; j < 8; ++j) {
      const int ci = t0 + j;
      const float dx = cc[ci * 3 + 0] - px, dy = cc[ci * 3 + 1] - py,
                  dz = cc[ci * 3 + 2] - pz;
      const float d = fmaf(dz, dz, fmaf(dy, dy, dx * dx));
      if (d <= Tval) {
        const unsigned slot = (cnt < (unsigned)CAP) ? cnt : (unsigned)(CAP - 1);
        scol[slot * TPB + tid] =
            (__float_as_uint(d) & 0xFFFFF000u) | (unsigned)(c0 + ci);
        cnt++;
      }
    }
  }
  if (cnt > (unsigned)CAP) {
    unsigned sf[17], cmf = UMAX;
#pragma unroll
    for (int j = 0; j < 17; ++j) sf[j] = UMAX;
    for (int ci = 0; ci < QTR; ++ci) {
      const float dx = cc[ci * 3 + 0] - px, dy = cc[ci * 3 + 1] - py,
                  dz = cc[ci * 3 + 2] - pz;
      const float d = fmaf(dz, dz, fmaf(dy, dy, dx * dx));
      insN<17>((__float_as_uint(d) & 0xFFFFF000u) | (unsigned)(c0 + ci), sf, cmf);
    }
#pragma unroll
    for (int j = 0; j < 17; ++j) scol[j * TPB + tid] = sf[j];
    cnt = 17;
  }
  scnt[tid] = cnt;
  __syncthreads();

  if (tid < PPB) {
    unsigned s16[16], cm16 = UMAX;
#pragma unroll
    for (int j = 0; j < 16; ++j) s16[j] = UMAX;
    const unsigned selfk = (unsigned)p;
#pragma unroll
    for (int k = 0; k < 4; ++k) {
      const int col = k * PPB + tid;
      const unsigned n = scnt[col];
      unsigned w = n;
#pragma unroll
      for (int off = 32; off >= 1; off >>= 1) {
        unsigned o = (unsigned)__shfl_xor((int)w, off, 64);
        w = (o > w) ? o : w;
      }
      for (unsigned j = 0; j < w; ++j) {
        unsigned kb = (j < n) ? scol[j * TPB + col] : UMAX;
        kb = (kb == selfk) ? UMAX : kb;
        insN<16>(kb, s16, cm16);
      }
    }
    float Sx = 0, Sy = 0, Sz = 0;
    float Sxx = 0, Sxy = 0, Sxz = 0, Syy = 0, Syz = 0, Szz = 0;
#pragma unroll
    for (int j = 0; j < 16; ++j) {
      const int idx = (int)(s16[j] & 0xFFFu);
      const float nx = xc[idx * 3 + 0], ny = xc[idx * 3 + 1], nz = xc[idx * 3 + 2];
      Sx += nx; Sy += ny; Sz += nz;
      Sxx = fmaf(nx, nx, Sxx); Sxy = fmaf(nx, ny, Sxy); Sxz = fmaf(nx, nz, Sxz);
      Syy = fmaf(ny, ny, Syy); Syz = fmaf(ny, nz, Syz); Szz = fmaf(nz, nz, Szz);
    }
    const float sc = 0.0625f;
    const float mx = Sx * sc, my = Sy * sc, mz = Sz * sc;
    const float cxx = fmaf(-mx, mx, Sxx * sc);
    const float cxy = fmaf(-mx, my, Sxy * sc);
    const float cxz = fmaf(-mx, mz, Sxz * sc);
    const float cyy = fmaf(-my, my, Syy * sc);
    const float cyz = fmaf(-my, mz, Syz * sc);
    const float czz = fmaf(-mz, mz, Szz * sc);

    const int gid = cloud * PTS + p;
    float4* o4 = (float4*)(out + (size_t)gid * 12);
    o4[0] = make_float4(px, py, pz, cxx);
    o4[1] = make_float4(cxy, cxz, cxy, cyy);
    o4[2] = make_float4(cyz, cxz, cyz, czz);
  }
}

extern "C" void kernel_launch(void* const* d_in, const int* in_sizes, int n_in,
                              void* d_out, int out_size, void* d_ws, size_t ws_size,
                              hipStream_t stream) {
  const float* x = (const float*)d_in[0];
  float* out = (float*)d_out;
  dim3 grid(NCLOUD * (PTS / PPB));  // 1024 blocks = 4/CU
  if (ws_size >= (size_t)NPAIRS * 8 * sizeof(float)) {
    float* ws = (float*)d_ws;
    pair_pack<<<NPAIRS / TPB, TPB, 0, stream>>>(x, ws);
    knn_cov_pk<<<grid, TPB, 0, stream>>>(ws, out);
  } else {
    knn_cov_aos<<<grid, TPB, 0, stream>>>(x, out);
  }
}